// Round 2
// baseline (327.437 us; speedup 1.0000x reference)
//
#include <hip/hip_runtime.h>

#define EMB 300
#define HID 10
#define BATCH 256
#define SEQ 512
#define ROWS (BATCH * SEQ)    // 131072
#define G3 (3 * HID)          // 30
#define KT 10                 // k-tiles of 32 (tile 9 offset 268, masked weights)
#define XP 36                 // padded LDS row stride (floats): 16B-aligned
#define PFD 4

#define NLOG2E 1.4426950408889634f   // log2(e)
#define TLOG2E 2.8853900817779268f   // 2*log2(e)

typedef __attribute__((ext_vector_type(8))) short short8;   // 8 bf16 = 4 VGPRs
typedef __attribute__((ext_vector_type(4))) float f32x4;    // MFMA C/D

__device__ __forceinline__ float fsig(float x) {
    float e = __builtin_amdgcn_exp2f(-NLOG2E * x);
    return __builtin_amdgcn_rcpf(1.0f + e);
}
__device__ __forceinline__ float ftanh(float x) {
    float e = __builtin_amdgcn_exp2f(TLOG2E * x);
    return fmaf(-2.0f, __builtin_amdgcn_rcpf(1.0f + e), 1.0f);
}
__device__ __forceinline__ float rdlane(float v, int lane) {
    return __int_as_float(__builtin_amdgcn_readlane(__float_as_int(v), lane));
}
__device__ __forceinline__ short bf16_hi(float f) {
    return (short)(__float_as_uint(f) >> 16);
}
__device__ __forceinline__ float bf16_tof(short h) {
    return __uint_as_float(((unsigned)(unsigned short)h) << 16);
}

// ---------------------------------------------------------------------------
// Prep: padded, k-tiled, split-bf16 weights wp[32 gates][320 k].
// ---------------------------------------------------------------------------
__global__ void k_prep(const float* __restrict__ w_ih,
                       short* __restrict__ wph, short* __restrict__ wpl) {
    int i = blockIdx.x * 256 + threadIdx.x;
    if (i >= 32 * 320) return;
    int g = i / 320, kk = i % 320;
    int kt = kk >> 5, ki = kk & 31;
    int k = (kt < 9) ? kk : 268 + ki;
    bool live = (g < 30) && ((kt < 9) ? (k < 300) : (ki >= 20));
    float v = live ? w_ih[g * EMB + k] : 0.0f;
    short hi = bf16_hi(v);
    float lo = v - bf16_tof(hi);
    wph[i] = hi;
    wpl[i] = bf16_hi(lo);
}

// ---------------------------------------------------------------------------
// Kernel 1: gi[row][g] via split-bf16 MFMA. v6: back to 2048 blocks (8/CU,
// 32 waves/CU TLP — the fused 1-block/CU version exposed all latency and ran
// 64 us for this phase). New: b_hh folded into r/z bias; epilogue pre-scales
// r/z by -log2(e) and n by 2*log2(e) so the scan's transcendental chains
// lose their leading multiplies.
// ---------------------------------------------------------------------------
__global__ __launch_bounds__(256) void k_gi(const float* __restrict__ x,
                                            const short* __restrict__ wph,
                                            const short* __restrict__ wpl,
                                            const float* __restrict__ b_ih,
                                            const float* __restrict__ b_hh,
                                            float* __restrict__ gi) {
    __shared__ float xs[64 * XP];                 // 9216 B
    const int t    = threadIdx.x;
    const int wave = t >> 6, lane = t & 63;
    const int m = lane & 15, q = lane >> 4;
    const int base = blockIdx.x * 64;             // first of 64 rows
    const int rloc = wave * 16 + m;               // this lane's fragment row

    // gates 0..15 are all r/z -> fold b_hh (added every step in the ref) in;
    // gates 20..29 (n) keep b_hh separate (it is scaled by r in the cell).
    const int g1 = 16 + m;
    const float bias0 = b_ih[m] + b_hh[m];
    const float bias1 = (g1 < G3) ? (b_ih[g1] + ((g1 < 20) ? b_hh[g1] : 0.0f))
                                  : 0.0f;
    f32x4 acc0 = {bias0, bias0, bias0, bias0};
    f32x4 acc1 = {bias1, bias1, bias1, bias1};

    const int srow  = t >> 3;                     // staging: 8 thr per row
    const int spiece = (t & 7) * 4;
    const float* __restrict__ xg0 = x + (size_t)(base + srow) * EMB + spiece;
    const float* __restrict__ xg1 = x + (size_t)(base + 32 + srow) * EMB + spiece;
    float* __restrict__ xs0 = xs + srow * XP + spiece;
    float* __restrict__ xs1 = xs + (32 + srow) * XP + spiece;

    const int wrow0 = m * 320;
    const int wrow1 = (16 + m) * 320;

#pragma unroll
    for (int kt = 0; kt < KT; kt++) {
        const int k0 = (kt < 9) ? kt * 32 : 268;  // in-row, never OOB
        __syncthreads();                          // prev tile's reads done
        *(float4*)xs0 = *(const float4*)(xg0 + k0);
        *(float4*)xs1 = *(const float4*)(xg1 + k0);
        __syncthreads();

        const float* fp = xs + rloc * XP + q * 8;
        const float4 xa = *(const float4*)fp;
        const float4 xb = *(const float4*)(fp + 4);
        float av[8] = {xa.x, xa.y, xa.z, xa.w, xb.x, xb.y, xb.z, xb.w};

        short8 ah, al;
#pragma unroll
        for (int j = 0; j < 8; j++) {
            short hi = bf16_hi(av[j]);
            ah[j] = hi;
            al[j] = bf16_hi(av[j] - bf16_tof(hi));
        }
        const int wo = kt * 32 + q * 8;
        short8 bh0 = *(const short8*)(wph + wrow0 + wo);
        short8 bl0 = *(const short8*)(wpl + wrow0 + wo);
        short8 bh1 = *(const short8*)(wph + wrow1 + wo);
        short8 bl1 = *(const short8*)(wpl + wrow1 + wo);

        acc0 = __builtin_amdgcn_mfma_f32_16x16x32_bf16(ah, bh0, acc0, 0, 0, 0);
        acc0 = __builtin_amdgcn_mfma_f32_16x16x32_bf16(al, bh0, acc0, 0, 0, 0);
        acc0 = __builtin_amdgcn_mfma_f32_16x16x32_bf16(ah, bl0, acc0, 0, 0, 0);
        acc1 = __builtin_amdgcn_mfma_f32_16x16x32_bf16(ah, bh1, acc1, 0, 0, 0);
        acc1 = __builtin_amdgcn_mfma_f32_16x16x32_bf16(al, bh1, acc1, 0, 0, 0);
        acc1 = __builtin_amdgcn_mfma_f32_16x16x32_bf16(ah, bl1, acc1, 0, 0, 0);
    }
    // pre-scale for the scan's exp2-direct gates:
    //   cols 0..19 (r,z): * -log2(e);  cols 20..29 (n): * 2*log2(e)
    const float sc0 = -NLOG2E;                    // cols m=0..15 are all r/z
    const float sc1 = (m < 4) ? -NLOG2E : TLOG2E; // cols 16..19 z, 20..29 n
#pragma unroll
    for (int r = 0; r < 4; r++) {
        const size_t row = (size_t)(base + wave * 16 + q * 4 + r);
        gi[row * 32 + m]      = acc0[r] * sc0;
        gi[row * 32 + 16 + m] = acc1[r] * sc1;
    }
}

// ---------------------------------------------------------------------------
// Kernel 2: stage gi slice to LDS, inline backward single-step (verified in
// round 1), then the forward scan. Scan v6: biases/scales pre-folded (chain
// loses 3 muls + 2 adds), and the h-broadcast uses 10 pipelined ds_swizzle
// lane-broadcasts instead of 10 serialized readlane->SGPR->VGPR round-trips.
// ---------------------------------------------------------------------------
__global__ __launch_bounds__(256) void k_scan(const float* __restrict__ gi,
                                              const float* __restrict__ w_hh,
                                              const float* __restrict__ b_hh,
                                              const float* __restrict__ x,
                                              const float* __restrict__ w_ih_b,
                                              const float* __restrict__ b_ih_b,
                                              const float* __restrict__ b_hh_b,
                                              const float* __restrict__ w_lin,
                                              const float* __restrict__ b_lin,
                                              float* __restrict__ out) {
    __shared__ float gs[SEQ * 32];                      // 64 KB
    __shared__ float gsum[G3];
    __shared__ float hbs[HID];
    const int b = blockIdx.x;
    const int t = threadIdx.x;

    const float4* __restrict__ src = (const float4*)(gi + (size_t)b * SEQ * 32);
#pragma unroll
    for (int i = 0; i < (SEQ * 32 / 4) / 256; i++)
        ((float4*)gs)[i * 256 + t] = src[i * 256 + t];

    // backward direction: one GRU step on x[:,511], h0=0 (no gs dependency,
    // runs under the staging's vmcnt shadow)
    if (t < G3 * 8) {
        const int g = t >> 3, jj = t & 7;
        const float* __restrict__ xrow = x + ((size_t)b * SEQ + (SEQ - 1)) * EMB;
        float acc = 0.0f;
#pragma unroll
        for (int i = 0; i < 10; ++i) {
            const int k = jj * 4 + i * 32;
            if (k < EMB) {
                const float4 wv = *(const float4*)(w_ih_b + (size_t)g * EMB + k);
                const float4 xv = *(const float4*)(xrow + k);
                acc = fmaf(xv.x, wv.x, acc);
                acc = fmaf(xv.y, wv.y, acc);
                acc = fmaf(xv.z, wv.z, acc);
                acc = fmaf(xv.w, wv.w, acc);
            }
        }
        acc += __shfl_down(acc, 4, 8);
        acc += __shfl_down(acc, 2, 8);
        acc += __shfl_down(acc, 1, 8);
        if (jj == 0) gsum[g] = acc + b_ih_b[g];
    }
    __syncthreads();                               // gs + gsum both ready
    if (t < HID) {
        const float r = fsig(gsum[t] + b_hh_b[t]);
        const float z = fsig(gsum[HID + t] + b_hh_b[HID + t]);
        const float n = ftanh(fmaf(r, b_hh_b[2 * HID + t], gsum[2 * HID + t]));
        hbs[t] = (1.0f - z) * n;
    }
    __syncthreads();
    if (t >= 64) return;

    // ---- forward recurrence, 1 wave, gi already in LDS, constants folded
    const int j = t;
    const int jc = (j < HID) ? j : HID - 1;

    float wr[HID], wz[HID], wn[HID];
#pragma unroll
    for (int k = 0; k < HID; k++) {
        wr[k] = -NLOG2E * w_hh[jc * HID + k];
        wz[k] = -NLOG2E * w_hh[(HID + jc) * HID + k];
        wn[k] =  TLOG2E * w_hh[(2 * HID + jc) * HID + k];
    }
    const float bn  = TLOG2E * b_hh[2 * HID + jc];  // r/z b_hh folded into gi
    const float hbv = hbs[jc];

    float pr[PFD], pz[PFD], pn[PFD];
#pragma unroll
    for (int d = 0; d < PFD; d++) {
        pr[d] = gs[d * 32 + jc];
        pz[d] = gs[d * 32 + HID + jc];
        pn[d] = gs[d * 32 + 2 * HID + jc];
    }

    float h = 0.0f;
    float hs[HID];
#pragma unroll
    for (int k = 0; k < HID; k++) hs[k] = 0.0f;

#define BCAST(K) hs[K] = __int_as_float(                                     \
        __builtin_amdgcn_ds_swizzle(hh, (K) << 5))   /* src lane = K (32-half) */

    for (int tt = 0; tt < SEQ; tt += PFD) {
#pragma unroll
        for (int d = 0; d < PFD; d++) {
            const float ir = pr[d], iz = pz[d], in_ = pn[d];

            int tn = tt + d + PFD;
            if (tn >= SEQ) tn = SEQ - 1;
            const float* __restrict__ gp = gs + tn * 32;
            pr[d] = gp[jc];
            pz[d] = gp[HID + jc];
            pn[d] = gp[2 * HID + jc];

            // 2-accumulator dots; ir/iz/in_ arrive pre-scaled, biases folded
            float ar0 = ir, ar1 = 0.0f;
            float az0 = iz, az1 = 0.0f;
            float an0 = bn, an1 = 0.0f;
#pragma unroll
            for (int k = 0; k < 5; k++) {
                ar0 = fmaf(wr[k], hs[k], ar0);
                az0 = fmaf(wz[k], hs[k], az0);
                an0 = fmaf(wn[k], hs[k], an0);
                ar1 = fmaf(wr[k + 5], hs[k + 5], ar1);
                az1 = fmaf(wz[k + 5], hs[k + 5], az1);
                an1 = fmaf(wn[k + 5], hs[k + 5], an1);
            }
            const float er = __builtin_amdgcn_exp2f(ar0 + ar1);
            const float r  = __builtin_amdgcn_rcpf(1.0f + er);
            const float ez = __builtin_amdgcn_exp2f(az0 + az1);
            const float z  = __builtin_amdgcn_rcpf(1.0f + ez);
            const float en = __builtin_amdgcn_exp2f(fmaf(r, an0 + an1, in_));
            const float n  = fmaf(-2.0f, __builtin_amdgcn_rcpf(1.0f + en), 1.0f);
            h = fmaf(z, h - n, n);                 // (1-z)*n + z*h

            const int hh = __float_as_int(h);
            BCAST(0); BCAST(1); BCAST(2); BCAST(3); BCAST(4);
            BCAST(5); BCAST(6); BCAST(7); BCAST(8); BCAST(9);
        }
    }
#undef BCAST

    const float p = fmaf(w_lin[jc], h, w_lin[HID + jc] * hbv);
    float s = 0.0f;
#pragma unroll
    for (int k = 0; k < HID; k++) s += rdlane(p, k);
    if (j == 0) out[b] = s + b_lin[0];
}

// ---------------------------------------------------------------------------
extern "C" void kernel_launch(void* const* d_in, const int* in_sizes, int n_in,
                              void* d_out, int out_size, void* d_ws, size_t ws_size,
                              hipStream_t stream) {
    const float* x      = (const float*)d_in[0];
    const float* w_ih_f = (const float*)d_in[1];
    const float* w_hh_f = (const float*)d_in[2];
    const float* b_ih_f = (const float*)d_in[3];
    const float* b_hh_f = (const float*)d_in[4];
    const float* w_ih_b = (const float*)d_in[5];
    const float* w_hh_b = (const float*)d_in[6];   // unused: backward is one step, h0=0
    const float* b_ih_b = (const float*)d_in[7];
    const float* b_hh_b = (const float*)d_in[8];
    const float* w_lin  = (const float*)d_in[9];
    const float* b_lin  = (const float*)d_in[10];
    float* out = (float*)d_out;

    float* gi  = (float*)d_ws;                          // [ROWS][32] = 16.78 MB
    short* wph = (short*)(gi + (size_t)ROWS * 32);      // [32][320] bf16-hi
    short* wpl = wph + 32 * 320;                        // [32][320] bf16-lo
    (void)w_hh_b; (void)in_sizes; (void)n_in; (void)out_size; (void)ws_size;

    k_prep<<<(32 * 320 + 255) / 256, 256, 0, stream>>>(w_ih_f, wph, wpl);
    k_gi  <<<ROWS / 64, 256, 0, stream>>>(x, wph, wpl, b_ih_f, b_hh_f, gi);
    k_scan<<<BATCH, 256, 0, stream>>>(gi, w_hh_f, b_hh_f, x,
                                      w_ih_b, b_ih_b, b_hh_b, w_lin, b_lin, out);
}